// Round 1
// baseline (258.419 us; speedup 1.0000x reference)
//
#include <hip/hip_runtime.h>
#include <hip/hip_fp16.h>

typedef int v4i __attribute__((ext_vector_type(4)));

#define QMAXF 127.0f
#define EPSF 1e-8f

#define BM 128
#define BN 128
#define BKB 128   // K-bytes (int8 elements) per LDS stage

// ---------------------------------------------------------------------------
// Per-row symmetric int8 quantization. One 256-thread block per row of 4096.
// WEIGHT=true: stored scale goes through fp16 roundtrip (quantization itself
// uses the pre-roundtrip fp32 scale, matching the reference).
// ---------------------------------------------------------------------------
template <bool WEIGHT>
__global__ __launch_bounds__(256) void quant_rows(
    const float* __restrict__ src, signed char* __restrict__ q,
    float* __restrict__ scale, int ncols) {
  const int row = blockIdx.x;
  const int t = threadIdx.x;
  const float4* s4 = (const float4*)(src + (size_t)row * ncols);

  float4 v[4];
  float am = 0.f;
#pragma unroll
  for (int p = 0; p < 4; ++p) {
    v[p] = s4[p * 256 + t];
    am = fmaxf(am, fmaxf(fmaxf(fabsf(v[p].x), fabsf(v[p].y)),
                         fmaxf(fabsf(v[p].z), fabsf(v[p].w))));
  }
  // wave (64-lane) butterfly max
#pragma unroll
  for (int off = 32; off > 0; off >>= 1) am = fmaxf(am, __shfl_xor(am, off));
  __shared__ float red[4];
  if ((t & 63) == 0) red[t >> 6] = am;
  __syncthreads();
  am = fmaxf(fmaxf(red[0], red[1]), fmaxf(red[2], red[3]));

  const float s = fmaxf(am, EPSF) / QMAXF;

  uint32_t* qrow = (uint32_t*)(q + (size_t)row * ncols);
#pragma unroll
  for (int p = 0; p < 4; ++p) {
    // IEEE fp32 division + rintf == jnp.round(x / s) (round-half-even)
    float fx = fminf(fmaxf(rintf(v[p].x / s), -QMAXF), QMAXF);
    float fy = fminf(fmaxf(rintf(v[p].y / s), -QMAXF), QMAXF);
    float fz = fminf(fmaxf(rintf(v[p].z / s), -QMAXF), QMAXF);
    float fw = fminf(fmaxf(rintf(v[p].w / s), -QMAXF), QMAXF);
    uint32_t packed = ((uint32_t)((int)fx & 0xff)) |
                      ((uint32_t)((int)fy & 0xff) << 8) |
                      ((uint32_t)((int)fz & 0xff) << 16) |
                      ((uint32_t)((int)fw & 0xff) << 24);
    qrow[p * 256 + t] = packed;
  }
  if (t == 0) {
    float so = s;
    if (WEIGHT) so = __half2float(__float2half(s));  // fp16 roundtrip
    scale[row] = so;
  }
}

// ---------------------------------------------------------------------------
// int8 GEMM: out[M][N] = dequant( xq[M][K] . wq[N][K]^T )
// ---------------------------------------------------------------------------
__device__ __forceinline__ void gload16(const void* g, void* l) {
  __builtin_amdgcn_global_load_lds(
      (const __attribute__((address_space(1))) void*)g,
      (__attribute__((address_space(3))) void*)l, 16, 0, 0);
}

__global__ __launch_bounds__(256) void gemm_i8(
    const signed char* __restrict__ A,  // xq [M][K]
    const signed char* __restrict__ B,  // wq [N][K]
    const float* __restrict__ xsc,      // [M]
    const float* __restrict__ wsc,      // [N]
    const float* __restrict__ bias,     // [N]
    float* __restrict__ out, int M, int N, int K) {
  __shared__ __align__(16) signed char As[BM][BKB];  // 16 KB
  __shared__ __align__(16) signed char Bs[BN][BKB];  // 16 KB

  const int tid = threadIdx.x;
  const int lane = tid & 63;
  const int wid = tid >> 6;
  const int wm = wid >> 1;  // 0..1
  const int wn = wid & 1;   // 0..1
  const int bm0 = blockIdx.x * BM;
  const int bn0 = blockIdx.y * BN;

  v4i acc[4][4];
#pragma unroll
  for (int i = 0; i < 4; ++i)
#pragma unroll
    for (int j = 0; j < 4; ++j) acc[i][j] = (v4i){0, 0, 0, 0};

  const int nkt = K / BKB;  // 32
  for (int kt = 0; kt < nkt; ++kt) {
#pragma unroll
    for (int j = 0; j < 4; ++j) {
      const int off = j * 4096 + tid * 16;
      const int row = off >> 7;
      const int col = off & 127;
      gload16(A + (size_t)(bm0 + row) * K + kt * BKB + col, ((char*)As) + off);
    }
#pragma unroll
    for (int j = 0; j < 4; ++j) {
      const int off = j * 4096 + tid * 16;
      const int row = off >> 7;
      const int col = off & 127;
      gload16(B + (size_t)(bn0 + row) * K + kt * BKB + col, ((char*)Bs) + off);
    }
    __syncthreads();

#pragma unroll
    for (int kk = 0; kk < 2; ++kk) {
      const int kb = kk * 64 + ((lane >> 4) << 4);
      v4i af[4], bf[4];
#pragma unroll
      for (int mi = 0; mi < 4; ++mi)
        af[mi] = *(const v4i*)&As[wm * 64 + mi * 16 + (lane & 15)][kb];
#pragma unroll
      for (int ni = 0; ni < 4; ++ni)
        bf[ni] = *(const v4i*)&Bs[wn * 64 + ni * 16 + (lane & 15)][kb];
#pragma unroll
      for (int mi = 0; mi < 4; ++mi)
#pragma unroll
        for (int ni = 0; ni < 4; ++ni)
          acc[mi][ni] = __builtin_amdgcn_mfma_i32_16x16x64_i8(
              af[mi], bf[ni], acc[mi][ni], 0, 0, 0);
    }
    __syncthreads();
  }

#pragma unroll
  for (int mi = 0; mi < 4; ++mi) {
    const int m0 = bm0 + wm * 64 + mi * 16 + ((lane >> 4) << 2);
    const float4 xs = *(const float4*)&xsc[m0];
    const float xsv[4] = {xs.x, xs.y, xs.z, xs.w};
#pragma unroll
    for (int ni = 0; ni < 4; ++ni) {
      const int n = bn0 + wn * 64 + ni * 16 + (lane & 15);
      const float wsn = wsc[n];
      const float bn_ = __half2float(__float2half(bias[n]));
#pragma unroll
      for (int r = 0; r < 4; ++r) {
        const float y = ((float)acc[mi][ni][r] * xsv[r]) * wsn + bn_;
        out[(size_t)(m0 + r) * N + n] = y;
      }
    }
  }
}

extern "C" void kernel_launch(void* const* d_in, const int* in_sizes, int n_in,
                              void* d_out, int out_size, void* d_ws,
                              size_t ws_size, hipStream_t stream) {
  const float* x = (const float*)d_in[0];     // [M][K] fp32
  const float* w = (const float*)d_in[1];     // [N][K] fp32
  const float* bias = (const float*)d_in[2];  // [N] fp32
  float* out = (float*)d_out;

  const int K = 4096;
  const int Nw = in_sizes[1] / K;  // 4096
  const int M = in_sizes[0] / K;   // 8192

  signed char* wq = (signed char*)d_ws;
  signed char* xq = wq + (size_t)Nw * K;
  float* wsc = (float*)(xq + (size_t)M * K);
  float* xsc = wsc + Nw;

  quant_rows<true><<<Nw, 256, 0, stream>>>(w, wq, wsc, K);
  quant_rows<false><<<M, 256, 0, stream>>>(x, xq, xsc, K);

  dim3 g2(M / BM, Nw / BN, 1);
  gemm_i8<<<g2, 256, 0, stream>>>(xq, wq, xsc, wsc, bias, out, M, Nw, K);
}

// Round 3
// 205.630 us; speedup vs baseline: 1.2567x; 1.2567x over previous
//
#include <hip/hip_runtime.h>
#include <hip/hip_fp16.h>

typedef int v4i __attribute__((ext_vector_type(4)));

#define QMAXF 127.0f
#define EPSF 1e-8f

// ---------------------------------------------------------------------------
// Per-row symmetric int8 quantization (validated round 1).
// ---------------------------------------------------------------------------
template <bool WEIGHT>
__global__ __launch_bounds__(256) void quant_rows(
    const float* __restrict__ src, signed char* __restrict__ q,
    float* __restrict__ scale, int ncols) {
  const int row = blockIdx.x;
  const int t = threadIdx.x;
  const float4* s4 = (const float4*)(src + (size_t)row * ncols);

  float4 v[4];
  float am = 0.f;
#pragma unroll
  for (int p = 0; p < 4; ++p) {
    v[p] = s4[p * 256 + t];
    am = fmaxf(am, fmaxf(fmaxf(fabsf(v[p].x), fabsf(v[p].y)),
                         fmaxf(fabsf(v[p].z), fabsf(v[p].w))));
  }
#pragma unroll
  for (int off = 32; off > 0; off >>= 1) am = fmaxf(am, __shfl_xor(am, off));
  __shared__ float red[4];
  if ((t & 63) == 0) red[t >> 6] = am;
  __syncthreads();
  am = fmaxf(fmaxf(red[0], red[1]), fmaxf(red[2], red[3]));

  const float s = fmaxf(am, EPSF) / QMAXF;

  uint32_t* qrow = (uint32_t*)(q + (size_t)row * ncols);
#pragma unroll
  for (int p = 0; p < 4; ++p) {
    float fx = fminf(fmaxf(rintf(v[p].x / s), -QMAXF), QMAXF);
    float fy = fminf(fmaxf(rintf(v[p].y / s), -QMAXF), QMAXF);
    float fz = fminf(fmaxf(rintf(v[p].z / s), -QMAXF), QMAXF);
    float fw = fminf(fmaxf(rintf(v[p].w / s), -QMAXF), QMAXF);
    uint32_t packed = ((uint32_t)((int)fx & 0xff)) |
                      ((uint32_t)((int)fy & 0xff) << 8) |
                      ((uint32_t)((int)fz & 0xff) << 16) |
                      ((uint32_t)((int)fw & 0xff) << 24);
    qrow[p * 256 + t] = packed;
  }
  if (t == 0) {
    float so = s;
    if (WEIGHT) so = __half2float(__float2half(s));
    scale[row] = so;
  }
}

// ---------------------------------------------------------------------------
// 256x256 8-phase int8 GEMM (T2 swizzle + T3/T4 counted-vmcnt + T5 setprio)
//   8 waves (2M x 4N), per-wave output 128x64, BK=128 bytes, LDS 128 KiB.
//   Race fix (round 3): tail drain vmcnt(0) at kt >= NKT-2 — when p2/p3 stop
//   staging, vmcnt(4) no longer covers SA1/SB1(NKT-1) before their readers.
// ---------------------------------------------------------------------------
__device__ __forceinline__ void gload16(const void* g, void* l) {
  __builtin_amdgcn_global_load_lds(
      (const __attribute__((address_space(1))) void*)g,
      (__attribute__((address_space(3))) void*)l, 16, 0, 0);
}

#define STAGE_A(dst, br0, ktoff)                                            \
  do {                                                                      \
    gload16(Ap + (size_t)((br0) + lr) * K + (ktoff) + scsw,                 \
            (dst) + ((br0) + lr) * 128 + sc);                               \
    gload16(Ap + (size_t)((br0) + 128 + lr) * K + (ktoff) + scsw,           \
            (dst) + ((br0) + 128 + lr) * 128 + sc);                         \
  } while (0)

#define STAGE_B(dst, nh, ktoff)                                             \
  do {                                                                      \
    const int r_ = (nh)*32 + lr + (lr & 32);                                \
    gload16(Bp + (size_t)(r_) * K + (ktoff) + scsw, (dst) + r_ * 128 + sc); \
    gload16(Bp + (size_t)(r_ + 128) * K + (ktoff) + scsw,                   \
            (dst) + (r_ + 128) * 128 + sc);                                 \
  } while (0)

// One phase: 12 ds_read_b128 -> stage issue -> barrier -> lgkmcnt(0) ->
// 16 MFMA (setprio-wrapped) -> PRE_BAR_STMT -> barrier.
#define PHASE(MH, NH, STAGE_STMT, PRE_BAR_STMT)                             \
  do {                                                                      \
    v4i af[4][2], bf[2][2];                                                 \
    _Pragma("unroll") for (int mi = 0; mi < 4; ++mi)                        \
        _Pragma("unroll") for (int ks = 0; ks < 2; ++ks)                    \
            af[mi][ks] = *(const v4i*)(Ad + (arow + ((MH)*4 + mi) * 16) *   \
                                                128 +                       \
                                       ((ac0 + ks * 64) ^ axor));           \
    _Pragma("unroll") for (int ni = 0; ni < 2; ++ni)                        \
        _Pragma("unroll") for (int ks = 0; ks < 2; ++ks)                    \
            bf[ni][ks] = *(const v4i*)(Bd + (brow + ((NH)*2 + ni) * 16) *   \
                                                128 +                       \
                                       ((ac0 + ks * 64) ^ bxor));           \
    STAGE_STMT;                                                             \
    __builtin_amdgcn_s_barrier();                                           \
    asm volatile("s_waitcnt lgkmcnt(0)" ::: "memory");                      \
    __builtin_amdgcn_sched_barrier(0);                                      \
    __builtin_amdgcn_s_setprio(1);                                          \
    _Pragma("unroll") for (int ks = 0; ks < 2; ++ks)                        \
        _Pragma("unroll") for (int mi = 0; mi < 4; ++mi)                    \
            _Pragma("unroll") for (int ni = 0; ni < 2; ++ni)                \
                acc[(MH)*4 + mi][(NH)*2 + ni] =                             \
                    __builtin_amdgcn_mfma_i32_16x16x64_i8(                  \
                        af[mi][ks], bf[ni][ks],                             \
                        acc[(MH)*4 + mi][(NH)*2 + ni], 0, 0, 0);            \
    __builtin_amdgcn_s_setprio(0);                                          \
    PRE_BAR_STMT;                                                           \
    __builtin_amdgcn_s_barrier();                                           \
  } while (0)

__global__ __launch_bounds__(512, 2) void gemm_i8(
    const signed char* __restrict__ A,  // xq [M][K]
    const signed char* __restrict__ B,  // wq [N][K]
    const float* __restrict__ xsc,      // [M]
    const float* __restrict__ wsc,      // [N]
    const float* __restrict__ bias,     // [N]
    float* __restrict__ out, int M, int N, int K) {
  __shared__ __align__(16) signed char lds[131072];
  signed char* const ldsA = lds;          // [2][256][128]
  signed char* const ldsB = lds + 65536;  // [2][256][128]

  const int tid = threadIdx.x;
  const int lane = tid & 63;
  const int wid = tid >> 6;  // 0..7
  const int wm = wid >> 2;   // 0..1
  const int wn = wid & 3;    // 0..3
  const int bm0 = blockIdx.x * 256;
  const int bn0 = blockIdx.y * 256;

  const signed char* Ap = A + (size_t)bm0 * K;
  const signed char* Bp = B + (size_t)bn0 * K;

  // staging geometry (per thread): one 16B chunk of a 64-row x 128B block
  const int lr = tid >> 3;                // 0..63 row within 8KB block
  const int sc = (tid & 7) << 4;          // linear dest col byte
  const int scsw = sc ^ ((lr & 7) << 4);  // pre-swizzled SOURCE col

  // read geometry (per lane)
  const int arow = wm * 128 + (lane & 15);
  const int brow = wn * 64 + (lane & 15);
  const int ac0 = (lane >> 4) << 4;  // 16B k-chunk within 64B ksub
  const int axor = (arow & 7) << 4;
  const int bxor = (brow & 7) << 4;

  v4i acc[8][4];
#pragma unroll
  for (int i = 0; i < 8; ++i)
#pragma unroll
    for (int j = 0; j < 4; ++j) acc[i][j] = (v4i){0, 0, 0, 0};

  const int NKT = K >> 7;  // 32 K-tiles of 128 bytes

  // ---- prologue: kt0 fully + {SA0,SB0}(kt1); drain to 4 outstanding ----
  STAGE_A(ldsA, 0, 0);            // SA0(0)
  STAGE_B(ldsB, 0, 0);            // SB0(0)
  STAGE_A(ldsA, 64, 0);           // SA1(0)
  STAGE_B(ldsB, 1, 0);            // SB1(0)
  STAGE_A(ldsA + 32768, 0, 128);  // SA0(1)
  STAGE_B(ldsB + 32768, 0, 128);  // SB0(1)
  asm volatile("s_waitcnt vmcnt(4)" ::: "memory");
  __builtin_amdgcn_sched_barrier(0);
  __builtin_amdgcn_s_barrier();

  for (int kt = 0; kt < NKT; ++kt) {
    const int d = kt & 1;
    const signed char* Ad = ldsA + d * 32768;
    const signed char* Bd = ldsB + d * 32768;
    signed char* const An = ldsA + (d ^ 1) * 32768;
    signed char* const Bn = ldsB + (d ^ 1) * 32768;
    const int ko1 = (kt + 1) << 7;
    const int ko2 = (kt + 2) << 7;

    // p0: quad(0,0) reads SA0+SB0(d); stage SA1(kt+1) -> buf d^1
    PHASE(0, 0, if (kt + 1 < NKT) STAGE_A(An, 64, ko1), {});
    // p1: quad(0,1) reads SA0+SB1(d); stage SB1(kt+1) -> buf d^1
    PHASE(0, 1, if (kt + 1 < NKT) STAGE_B(Bn, 1, ko1), {});
    // p2: quad(1,0) reads SA1+SB0(d); stage SA0(kt+2) -> buf d (region free)
    PHASE(1, 0, if (kt + 2 < NKT) STAGE_A((signed char*)Ad, 0, ko2), {});
    // p3: quad(1,1) reads SA1+SB1(d); stage SB0(kt+2) -> buf d (region free)
    // Boundary wait: counted in steady state; FULL drain once p2/p3 stop
    // staging (kt >= NKT-2), else last tile's SA1/SB1 are never waited on.
    PHASE(1, 1, if (kt + 2 < NKT) STAGE_B((signed char*)Bd, 0, ko2), {
      if (kt < NKT - 2) {
        asm volatile("s_waitcnt vmcnt(4)" ::: "memory");
      } else {
        asm volatile("s_waitcnt vmcnt(0)" ::: "memory");
      }
      __builtin_amdgcn_sched_barrier(0);
    });
  }

  // ---- epilogue: dequant + fp16-roundtripped bias, fp32 store ----
#pragma unroll
  for (int mi = 0; mi < 8; ++mi) {
    const int m0 = bm0 + wm * 128 + mi * 16 + ((lane >> 4) << 2);
    const float4 xs = *(const float4*)&xsc[m0];
    const float xsv[4] = {xs.x, xs.y, xs.z, xs.w};
#pragma unroll
    for (int ni = 0; ni < 4; ++ni) {
      const int n = bn0 + wn * 64 + ni * 16 + (lane & 15);
      const float wsn = wsc[n];
      const float bn_ = __half2float(__float2half(bias[n]));
#pragma unroll
      for (int r = 0; r < 4; ++r) {
        out[(size_t)(m0 + r) * N + n] =
            (float)acc[mi][ni][r] * xsv[r] * wsn + bn_;
      }
    }
  }
}

extern "C" void kernel_launch(void* const* d_in, const int* in_sizes, int n_in,
                              void* d_out, int out_size, void* d_ws,
                              size_t ws_size, hipStream_t stream) {
  const float* x = (const float*)d_in[0];     // [M][K] fp32
  const float* w = (const float*)d_in[1];     // [N][K] fp32
  const float* bias = (const float*)d_in[2];  // [N] fp32
  float* out = (float*)d_out;

  const int K = 4096;
  const int Nw = in_sizes[1] / K;  // 4096
  const int M = in_sizes[0] / K;   // 8192

  signed char* wq = (signed char*)d_ws;
  signed char* xq = wq + (size_t)Nw * K;
  float* wsc = (float*)(xq + (size_t)M * K);
  float* xsc = wsc + Nw;

  quant_rows<true><<<Nw, 256, 0, stream>>>(w, wq, wsc, K);
  quant_rows<false><<<M, 256, 0, stream>>>(x, xq, xsc, K);

  dim3 g2(M / 256, Nw / 256, 1);
  gemm_i8<<<g2, 512, 0, stream>>>(xq, wq, xsc, wsc, bias, out, M, Nw, K);
}

// Round 4
// 196.264 us; speedup vs baseline: 1.3167x; 1.0477x over previous
//
#include <hip/hip_runtime.h>
#include <hip/hip_fp16.h>

typedef int v4i __attribute__((ext_vector_type(4)));

#define QMAXF 127.0f
#define EPSF 1e-8f

// ---------------------------------------------------------------------------
// Per-row symmetric int8 quantization (validated round 1).
// ---------------------------------------------------------------------------
template <bool WEIGHT>
__global__ __launch_bounds__(256) void quant_rows(
    const float* __restrict__ src, signed char* __restrict__ q,
    float* __restrict__ scale, int ncols) {
  const int row = blockIdx.x;
  const int t = threadIdx.x;
  const float4* s4 = (const float4*)(src + (size_t)row * ncols);

  float4 v[4];
  float am = 0.f;
#pragma unroll
  for (int p = 0; p < 4; ++p) {
    v[p] = s4[p * 256 + t];
    am = fmaxf(am, fmaxf(fmaxf(fabsf(v[p].x), fabsf(v[p].y)),
                         fmaxf(fabsf(v[p].z), fabsf(v[p].w))));
  }
#pragma unroll
  for (int off = 32; off > 0; off >>= 1) am = fmaxf(am, __shfl_xor(am, off));
  __shared__ float red[4];
  if ((t & 63) == 0) red[t >> 6] = am;
  __syncthreads();
  am = fmaxf(fmaxf(red[0], red[1]), fmaxf(red[2], red[3]));

  const float s = fmaxf(am, EPSF) / QMAXF;

  uint32_t* qrow = (uint32_t*)(q + (size_t)row * ncols);
#pragma unroll
  for (int p = 0; p < 4; ++p) {
    float fx = fminf(fmaxf(rintf(v[p].x / s), -QMAXF), QMAXF);
    float fy = fminf(fmaxf(rintf(v[p].y / s), -QMAXF), QMAXF);
    float fz = fminf(fmaxf(rintf(v[p].z / s), -QMAXF), QMAXF);
    float fw = fminf(fmaxf(rintf(v[p].w / s), -QMAXF), QMAXF);
    uint32_t packed = ((uint32_t)((int)fx & 0xff)) |
                      ((uint32_t)((int)fy & 0xff) << 8) |
                      ((uint32_t)((int)fz & 0xff) << 16) |
                      ((uint32_t)((int)fw & 0xff) << 24);
    qrow[p * 256 + t] = packed;
  }
  if (t == 0) {
    float so = s;
    if (WEIGHT) so = __half2float(__float2half(s));
    scale[row] = so;
  }
}

// ---------------------------------------------------------------------------
// 256x256 8-wave int8 GEMM. Round-4 change: fragment reuse — per-phase
// ds_read_b128 count goes 12/12/12/12 -> 12/4/8/0 (A-half held 2 phases,
// B-half held 2 phases). Stage schedule + vmcnt ledger identical to the
// validated round-3 kernel. Plus XCD-aware block swizzle (T1).
// ---------------------------------------------------------------------------
__device__ __forceinline__ void gload16(const void* g, void* l) {
  __builtin_amdgcn_global_load_lds(
      (const __attribute__((address_space(1))) void*)g,
      (__attribute__((address_space(3))) void*)l, 16, 0, 0);
}

#define STAGE_A(dst, br0, ktoff)                                            \
  do {                                                                      \
    gload16(Ap + (size_t)((br0) + lr) * K + (ktoff) + scsw,                 \
            (dst) + ((br0) + lr) * 128 + sc);                               \
    gload16(Ap + (size_t)((br0) + 128 + lr) * K + (ktoff) + scsw,           \
            (dst) + ((br0) + 128 + lr) * 128 + sc);                         \
  } while (0)

#define STAGE_B(dst, nh, ktoff)                                             \
  do {                                                                      \
    const int r_ = (nh)*32 + lr + (lr & 32);                                \
    gload16(Bp + (size_t)(r_) * K + (ktoff) + scsw, (dst) + r_ * 128 + sc); \
    gload16(Bp + (size_t)(r_ + 128) * K + (ktoff) + scsw,                   \
            (dst) + (r_ + 128) * 128 + sc);                                 \
  } while (0)

// A-fragment set for half MH (8 x ds_read_b128 into af[4][2])
#define READ_AF(MH)                                                         \
  _Pragma("unroll") for (int mi = 0; mi < 4; ++mi)                          \
      _Pragma("unroll") for (int ks = 0; ks < 2; ++ks)                      \
          af[mi][ks] = *(const v4i*)(Ad + (arow + ((MH)*4 + mi) * 16) *     \
                                              128 +                        \
                                     ((ac0 + ks * 64) ^ axor))

// B-fragment set for half NH (4 x ds_read_b128 into dst[2][2])
#define READ_BF(dst, NH)                                                    \
  _Pragma("unroll") for (int ni = 0; ni < 2; ++ni)                          \
      _Pragma("unroll") for (int ks = 0; ks < 2; ++ks)                      \
          dst[ni][ks] = *(const v4i*)(Bd + (brow + ((NH)*2 + ni) * 16) *    \
                                               128 +                       \
                                      ((ac0 + ks * 64) ^ bxor))

// One phase: READS -> stage issue -> barrier -> lgkmcnt(0) -> 16 MFMA ->
// PRE_BAR -> barrier.  MFMA uses held af + the given bf set.
#define PHASE(MH, NH, BFREG, READS_STMT, STAGE_STMT, PRE_BAR_STMT)          \
  do {                                                                      \
    READS_STMT;                                                             \
    STAGE_STMT;                                                             \
    __builtin_amdgcn_s_barrier();                                           \
    asm volatile("s_waitcnt lgkmcnt(0)" ::: "memory");                      \
    __builtin_amdgcn_sched_barrier(0);                                      \
    __builtin_amdgcn_s_setprio(1);                                          \
    _Pragma("unroll") for (int ks = 0; ks < 2; ++ks)                        \
        _Pragma("unroll") for (int mi = 0; mi < 4; ++mi)                    \
            _Pragma("unroll") for (int ni = 0; ni < 2; ++ni)                \
                acc[(MH)*4 + mi][(NH)*2 + ni] =                             \
                    __builtin_amdgcn_mfma_i32_16x16x64_i8(                  \
                        af[mi][ks], BFREG[ni][ks],                          \
                        acc[(MH)*4 + mi][(NH)*2 + ni], 0, 0, 0);            \
    __builtin_amdgcn_s_setprio(0);                                          \
    PRE_BAR_STMT;                                                           \
    __builtin_amdgcn_s_barrier();                                           \
  } while (0)

__global__ __launch_bounds__(512, 2) void gemm_i8(
    const signed char* __restrict__ A,  // xq [M][K]
    const signed char* __restrict__ B,  // wq [N][K]
    const float* __restrict__ xsc,      // [M]
    const float* __restrict__ wsc,      // [N]
    const float* __restrict__ bias,     // [N]
    float* __restrict__ out, int M, int N, int K) {
  __shared__ __align__(16) signed char lds[131072];
  signed char* const ldsA = lds;          // [2][256][128]
  signed char* const ldsB = lds + 65536;  // [2][256][128]

  const int tid = threadIdx.x;
  const int lane = tid & 63;
  const int wid = tid >> 6;  // 0..7
  const int wm = wid >> 2;   // 0..1
  const int wn = wid & 3;    // 0..3

  // XCD-aware chunked swizzle (nwg=512, 512%8==0 -> simple bijective remap).
  const int nbx = M >> 8;  // 32
  const int wg = blockIdx.x;
  const int swz = (wg & 7) * ((M >> 8) * (N >> 8) / 8) + (wg >> 3);
  const int bm0 = (swz % nbx) * 256;
  const int bn0 = (swz / nbx) * 256;

  const signed char* Ap = A + (size_t)bm0 * K;
  const signed char* Bp = B + (size_t)bn0 * K;

  // staging geometry (per thread): one 16B chunk of a 64-row x 128B block
  const int lr = tid >> 3;                // 0..63 row within 8KB block
  const int sc = (tid & 7) << 4;          // linear dest col byte
  const int scsw = sc ^ ((lr & 7) << 4);  // pre-swizzled SOURCE col

  // read geometry (per lane)
  const int arow = wm * 128 + (lane & 15);
  const int brow = wn * 64 + (lane & 15);
  const int ac0 = (lane >> 4) << 4;  // 16B k-chunk within 64B ksub
  const int axor = (arow & 7) << 4;
  const int bxor = (brow & 7) << 4;

  v4i acc[8][4];
#pragma unroll
  for (int i = 0; i < 8; ++i)
#pragma unroll
    for (int j = 0; j < 4; ++j) acc[i][j] = (v4i){0, 0, 0, 0};

  const int NKT = K >> 7;  // 32 K-tiles of 128 bytes

  // ---- prologue: kt0 fully + {SA0,SB0}(kt1); drain to 4 outstanding ----
  STAGE_A(ldsA, 0, 0);            // SA0(0)
  STAGE_B(ldsB, 0, 0);            // SB0(0)
  STAGE_A(ldsA, 64, 0);           // SA1(0)
  STAGE_B(ldsB, 1, 0);            // SB1(0)
  STAGE_A(ldsA + 32768, 0, 128);  // SA0(1)
  STAGE_B(ldsB + 32768, 0, 128);  // SB0(1)
  asm volatile("s_waitcnt vmcnt(4)" ::: "memory");
  __builtin_amdgcn_sched_barrier(0);
  __builtin_amdgcn_s_barrier();

  for (int kt = 0; kt < NKT; ++kt) {
    const int d = kt & 1;
    const signed char* Ad = ldsA + d * 32768;
    const signed char* Bd = ldsB + d * 32768;
    signed char* const An = ldsA + (d ^ 1) * 32768;
    signed char* const Bn = ldsB + (d ^ 1) * 32768;
    const int ko1 = (kt + 1) << 7;
    const int ko2 = (kt + 2) << 7;

    v4i af[4][2];   // A-half fragments (held 2 phases)
    v4i bf0[2][2];  // B NH=0 fragments (held p0..p2)
    v4i bf1[2][2];  // B NH=1 fragments (held p1..p3)

    // p0: quad(0,0); reads A-MH0 (8) + B-NH0 (4); stage SA1(kt+1)->buf d^1
    PHASE(0, 0, bf0, { READ_AF(0); READ_BF(bf0, 0); },
          if (kt + 1 < NKT) STAGE_A(An, 64, ko1), {});
    // p1: quad(0,1); reads B-NH1 (4), af held; stage SB1(kt+1)->buf d^1
    PHASE(0, 1, bf1, { READ_BF(bf1, 1); },
          if (kt + 1 < NKT) STAGE_B(Bn, 1, ko1), {});
    // p2: quad(1,0); reads A-MH1 (8), bf0 held; stage SA0(kt+2)->buf d
    PHASE(1, 0, bf0, { READ_AF(1); },
          if (kt + 2 < NKT) STAGE_A((signed char*)Ad, 0, ko2), {});
    // p3: quad(1,1); no reads (af, bf1 held); stage SB0(kt+2)->buf d
    // Boundary wait: counted in steady state; FULL drain once staging stops.
    PHASE(1, 1, bf1, {},
          if (kt + 2 < NKT) STAGE_B((signed char*)Bd, 0, ko2), {
            if (kt < NKT - 2) {
              asm volatile("s_waitcnt vmcnt(4)" ::: "memory");
            } else {
              asm volatile("s_waitcnt vmcnt(0)" ::: "memory");
            }
            __builtin_amdgcn_sched_barrier(0);
          });
  }

  // ---- epilogue: dequant + fp16-roundtripped bias, fp32 store ----
#pragma unroll
  for (int mi = 0; mi < 8; ++mi) {
    const int m0 = bm0 + wm * 128 + mi * 16 + ((lane >> 4) << 2);
    const float4 xs = *(const float4*)&xsc[m0];
    const float xsv[4] = {xs.x, xs.y, xs.z, xs.w};
#pragma unroll
    for (int ni = 0; ni < 4; ++ni) {
      const int n = bn0 + wn * 64 + ni * 16 + (lane & 15);
      const float wsn = wsc[n];
      const float bn_ = __half2float(__float2half(bias[n]));
#pragma unroll
      for (int r = 0; r < 4; ++r) {
        out[(size_t)(m0 + r) * N + n] =
            (float)acc[mi][ni][r] * xsv[r] * wsn + bn_;
      }
    }
  }
}

extern "C" void kernel_launch(void* const* d_in, const int* in_sizes, int n_in,
                              void* d_out, int out_size, void* d_ws,
                              size_t ws_size, hipStream_t stream) {
  const float* x = (const float*)d_in[0];     // [M][K] fp32
  const float* w = (const float*)d_in[1];     // [N][K] fp32
  const float* bias = (const float*)d_in[2];  // [N] fp32
  float* out = (float*)d_out;

  const int K = 4096;
  const int Nw = in_sizes[1] / K;  // 4096
  const int M = in_sizes[0] / K;   // 8192

  signed char* wq = (signed char*)d_ws;
  signed char* xq = wq + (size_t)Nw * K;
  float* wsc = (float*)(xq + (size_t)M * K);
  float* xsc = wsc + Nw;

  quant_rows<true><<<Nw, 256, 0, stream>>>(w, wq, wsc, K);
  quant_rows<false><<<M, 256, 0, stream>>>(x, xq, xsc, K);

  const int nwg = (M / 256) * (Nw / 256);  // 512
  gemm_i8<<<nwg, 512, 0, stream>>>(xq, wq, xsc, wsc, bias, out, M, Nw, K);
}

// Round 5
// 179.780 us; speedup vs baseline: 1.4374x; 1.0917x over previous
//
#include <hip/hip_runtime.h>
#include <hip/hip_fp16.h>

typedef int v4i __attribute__((ext_vector_type(4)));

#define QMAXF 127.0f
#define EPSF 1e-8f

// ---------------------------------------------------------------------------
// Per-row symmetric int8 quantization (validated round 1).
// ---------------------------------------------------------------------------
template <bool WEIGHT>
__global__ __launch_bounds__(256) void quant_rows(
    const float* __restrict__ src, signed char* __restrict__ q,
    float* __restrict__ scale, int ncols) {
  const int row = blockIdx.x;
  const int t = threadIdx.x;
  const float4* s4 = (const float4*)(src + (size_t)row * ncols);

  float4 v[4];
  float am = 0.f;
#pragma unroll
  for (int p = 0; p < 4; ++p) {
    v[p] = s4[p * 256 + t];
    am = fmaxf(am, fmaxf(fmaxf(fabsf(v[p].x), fabsf(v[p].y)),
                         fmaxf(fabsf(v[p].z), fabsf(v[p].w))));
  }
#pragma unroll
  for (int off = 32; off > 0; off >>= 1) am = fmaxf(am, __shfl_xor(am, off));
  __shared__ float red[4];
  if ((t & 63) == 0) red[t >> 6] = am;
  __syncthreads();
  am = fmaxf(fmaxf(red[0], red[1]), fmaxf(red[2], red[3]));

  const float s = fmaxf(am, EPSF) / QMAXF;

  uint32_t* qrow = (uint32_t*)(q + (size_t)row * ncols);
#pragma unroll
  for (int p = 0; p < 4; ++p) {
    float fx = fminf(fmaxf(rintf(v[p].x / s), -QMAXF), QMAXF);
    float fy = fminf(fmaxf(rintf(v[p].y / s), -QMAXF), QMAXF);
    float fz = fminf(fmaxf(rintf(v[p].z / s), -QMAXF), QMAXF);
    float fw = fminf(fmaxf(rintf(v[p].w / s), -QMAXF), QMAXF);
    uint32_t packed = ((uint32_t)((int)fx & 0xff)) |
                      ((uint32_t)((int)fy & 0xff) << 8) |
                      ((uint32_t)((int)fz & 0xff) << 16) |
                      ((uint32_t)((int)fw & 0xff) << 24);
    qrow[p * 256 + t] = packed;
  }
  if (t == 0) {
    float so = s;
    if (WEIGHT) so = __half2float(__float2half(s));
    scale[row] = so;
  }
}

// ---------------------------------------------------------------------------
// 256x256 8-wave int8 GEMM.
// Round-5 changes vs validated round-4:
//  (a) remove mid-phase barrier + forced lgkmcnt(0): compiler interleaves
//      MFMA with its own counted lgkm waits -> LDS reads overlap MFMA.
//      Safety: every ds_read has an in-phase consumer MFMA, so reads drain
//      before the wave reaches the phase-end barrier; region-overwrite
//      hazards only need phase-end barriers (readers of SA0/SB0(d) are in
//      p0; overwriting stages are p2/p3, >=2 barriers later).
//  (b) revert XCD swizzle (round-4 chunking swept all A-panels per XCD ->
//      FETCH 270 MB); plain m-fast 2D grid measured 98 MB.
//  vmcnt ledger identical to round 3/4 (counted vmcnt(4); tail drain 0).
// ---------------------------------------------------------------------------
__device__ __forceinline__ void gload16(const void* g, void* l) {
  __builtin_amdgcn_global_load_lds(
      (const __attribute__((address_space(1))) void*)g,
      (__attribute__((address_space(3))) void*)l, 16, 0, 0);
}

#define STAGE_A(dst, br0, ktoff)                                            \
  do {                                                                      \
    gload16(Ap + (size_t)((br0) + lr) * K + (ktoff) + scsw,                 \
            (dst) + ((br0) + lr) * 128 + sc);                               \
    gload16(Ap + (size_t)((br0) + 128 + lr) * K + (ktoff) + scsw,           \
            (dst) + ((br0) + 128 + lr) * 128 + sc);                         \
  } while (0)

#define STAGE_B(dst, nh, ktoff)                                             \
  do {                                                                      \
    const int r_ = (nh)*32 + lr + (lr & 32);                                \
    gload16(Bp + (size_t)(r_) * K + (ktoff) + scsw, (dst) + r_ * 128 + sc); \
    gload16(Bp + (size_t)(r_ + 128) * K + (ktoff) + scsw,                   \
            (dst) + (r_ + 128) * 128 + sc);                                 \
  } while (0)

// A-fragment set for half MH (8 x ds_read_b128 into af[4][2])
#define READ_AF(MH)                                                         \
  _Pragma("unroll") for (int mi = 0; mi < 4; ++mi)                          \
      _Pragma("unroll") for (int ks = 0; ks < 2; ++ks)                      \
          af[mi][ks] = *(const v4i*)(Ad + (arow + ((MH)*4 + mi) * 16) *     \
                                              128 +                        \
                                     ((ac0 + ks * 64) ^ axor))

// B-fragment set for half NH (4 x ds_read_b128 into dst[2][2])
#define READ_BF(dst, NH)                                                    \
  _Pragma("unroll") for (int ni = 0; ni < 2; ++ni)                          \
      _Pragma("unroll") for (int ks = 0; ks < 2; ++ks)                      \
          dst[ni][ks] = *(const v4i*)(Bd + (brow + ((NH)*2 + ni) * 16) *    \
                                               128 +                       \
                                      ((ac0 + ks * 64) ^ bxor))

// One phase: READS -> stage issue -> 16 MFMA (compiler-scheduled lgkm
// waits overlap reads with MFMA) -> PRE_BAR -> barrier.
#define PHASE(MH, NH, BFREG, READS_STMT, STAGE_STMT, PRE_BAR_STMT)          \
  do {                                                                      \
    READS_STMT;                                                             \
    STAGE_STMT;                                                             \
    __builtin_amdgcn_s_setprio(1);                                          \
    _Pragma("unroll") for (int ks = 0; ks < 2; ++ks)                        \
        _Pragma("unroll") for (int mi = 0; mi < 4; ++mi)                    \
            _Pragma("unroll") for (int ni = 0; ni < 2; ++ni)                \
                acc[(MH)*4 + mi][(NH)*2 + ni] =                             \
                    __builtin_amdgcn_mfma_i32_16x16x64_i8(                  \
                        af[mi][ks], BFREG[ni][ks],                          \
                        acc[(MH)*4 + mi][(NH)*2 + ni], 0, 0, 0);            \
    __builtin_amdgcn_s_setprio(0);                                          \
    PRE_BAR_STMT;                                                           \
    __builtin_amdgcn_s_barrier();                                           \
  } while (0)

__global__ __launch_bounds__(512, 2) void gemm_i8(
    const signed char* __restrict__ A,  // xq [M][K]
    const signed char* __restrict__ B,  // wq [N][K]
    const float* __restrict__ xsc,      // [M]
    const float* __restrict__ wsc,      // [N]
    const float* __restrict__ bias,     // [N]
    float* __restrict__ out, int M, int N, int K) {
  __shared__ __align__(16) signed char lds[131072];
  signed char* const ldsA = lds;          // [2][256][128]
  signed char* const ldsB = lds + 65536;  // [2][256][128]

  const int tid = threadIdx.x;
  const int lane = tid & 63;
  const int wid = tid >> 6;  // 0..7
  const int wm = wid >> 2;   // 0..1
  const int wn = wid & 3;    // 0..3
  const int bm0 = blockIdx.x * 256;
  const int bn0 = blockIdx.y * 256;

  const signed char* Ap = A + (size_t)bm0 * K;
  const signed char* Bp = B + (size_t)bn0 * K;

  // staging geometry (per thread): one 16B chunk of a 64-row x 128B block
  const int lr = tid >> 3;                // 0..63 row within 8KB block
  const int sc = (tid & 7) << 4;          // linear dest col byte
  const int scsw = sc ^ ((lr & 7) << 4);  // pre-swizzled SOURCE col

  // read geometry (per lane)
  const int arow = wm * 128 + (lane & 15);
  const int brow = wn * 64 + (lane & 15);
  const int ac0 = (lane >> 4) << 4;  // 16B k-chunk within 64B ksub
  const int axor = (arow & 7) << 4;
  const int bxor = (brow & 7) << 4;

  v4i acc[8][4];
#pragma unroll
  for (int i = 0; i < 8; ++i)
#pragma unroll
    for (int j = 0; j < 4; ++j) acc[i][j] = (v4i){0, 0, 0, 0};

  const int NKT = K >> 7;  // 32 K-tiles of 128 bytes

  // ---- prologue: kt0 fully + {SA0,SB0}(kt1); drain to 4 outstanding ----
  STAGE_A(ldsA, 0, 0);            // SA0(0)
  STAGE_B(ldsB, 0, 0);            // SB0(0)
  STAGE_A(ldsA, 64, 0);           // SA1(0)
  STAGE_B(ldsB, 1, 0);            // SB1(0)
  STAGE_A(ldsA + 32768, 0, 128);  // SA0(1)
  STAGE_B(ldsB + 32768, 0, 128);  // SB0(1)
  asm volatile("s_waitcnt vmcnt(4)" ::: "memory");
  __builtin_amdgcn_sched_barrier(0);
  __builtin_amdgcn_s_barrier();

  for (int kt = 0; kt < NKT; ++kt) {
    const int d = kt & 1;
    const signed char* Ad = ldsA + d * 32768;
    const signed char* Bd = ldsB + d * 32768;
    signed char* const An = ldsA + (d ^ 1) * 32768;
    signed char* const Bn = ldsB + (d ^ 1) * 32768;
    const int ko1 = (kt + 1) << 7;
    const int ko2 = (kt + 2) << 7;

    v4i af[4][2];   // A-half fragments (held 2 phases)
    v4i bf0[2][2];  // B NH=0 fragments (held p0..p2)
    v4i bf1[2][2];  // B NH=1 fragments (held p1..p3)

    // p0: quad(0,0); reads A-MH0 (8) + B-NH0 (4); stage SA1(kt+1)->buf d^1
    PHASE(0, 0, bf0, { READ_AF(0); READ_BF(bf0, 0); },
          if (kt + 1 < NKT) STAGE_A(An, 64, ko1), {});
    // p1: quad(0,1); reads B-NH1 (4), af held; stage SB1(kt+1)->buf d^1
    PHASE(0, 1, bf1, { READ_BF(bf1, 1); },
          if (kt + 1 < NKT) STAGE_B(Bn, 1, ko1), {});
    // p2: quad(1,0); reads A-MH1 (8), bf0 held; stage SA0(kt+2)->buf d
    PHASE(1, 0, bf0, { READ_AF(1); },
          if (kt + 2 < NKT) STAGE_A((signed char*)Ad, 0, ko2), {});
    // p3: quad(1,1); no reads (af, bf1 held); stage SB0(kt+2)->buf d
    // Boundary wait: counted in steady state; FULL drain once staging stops.
    PHASE(1, 1, bf1, {},
          if (kt + 2 < NKT) STAGE_B((signed char*)Bd, 0, ko2), {
            if (kt < NKT - 2) {
              asm volatile("s_waitcnt vmcnt(4)" ::: "memory");
            } else {
              asm volatile("s_waitcnt vmcnt(0)" ::: "memory");
            }
            __builtin_amdgcn_sched_barrier(0);
          });
  }

  // ---- epilogue: dequant + fp16-roundtripped bias, fp32 store ----
#pragma unroll
  for (int mi = 0; mi < 8; ++mi) {
    const int m0 = bm0 + wm * 128 + mi * 16 + ((lane >> 4) << 2);
    const float4 xs = *(const float4*)&xsc[m0];
    const float xsv[4] = {xs.x, xs.y, xs.z, xs.w};
#pragma unroll
    for (int ni = 0; ni < 4; ++ni) {
      const int n = bn0 + wn * 64 + ni * 16 + (lane & 15);
      const float wsn = wsc[n];
      const float bn_ = __half2float(__float2half(bias[n]));
#pragma unroll
      for (int r = 0; r < 4; ++r) {
        out[(size_t)(m0 + r) * N + n] =
            (float)acc[mi][ni][r] * xsv[r] * wsn + bn_;
      }
    }
  }
}

extern "C" void kernel_launch(void* const* d_in, const int* in_sizes, int n_in,
                              void* d_out, int out_size, void* d_ws,
                              size_t ws_size, hipStream_t stream) {
  const float* x = (const float*)d_in[0];     // [M][K] fp32
  const float* w = (const float*)d_in[1];     // [N][K] fp32
  const float* bias = (const float*)d_in[2];  // [N] fp32
  float* out = (float*)d_out;

  const int K = 4096;
  const int Nw = in_sizes[1] / K;  // 4096
  const int M = in_sizes[0] / K;   // 8192

  signed char* wq = (signed char*)d_ws;
  signed char* xq = wq + (size_t)Nw * K;
  float* wsc = (float*)(xq + (size_t)M * K);
  float* xsc = wsc + Nw;

  quant_rows<true><<<Nw, 256, 0, stream>>>(w, wq, wsc, K);
  quant_rows<false><<<M, 256, 0, stream>>>(x, xq, xsc, K);

  dim3 g2(M / 256, Nw / 256, 1);
  gemm_i8<<<g2, 512, 0, stream>>>(xq, wq, xsc, wsc, bias, out, M, Nw, K);
}

// Round 6
// 178.527 us; speedup vs baseline: 1.4475x; 1.0070x over previous
//
#include <hip/hip_runtime.h>
#include <hip/hip_fp16.h>

typedef int v4i __attribute__((ext_vector_type(4)));

#define QMAXF 127.0f
#define EPSF 1e-8f

// ---------------------------------------------------------------------------
// Per-row symmetric int8 quantization (validated round 1).
// ---------------------------------------------------------------------------
template <bool WEIGHT>
__global__ __launch_bounds__(256) void quant_rows(
    const float* __restrict__ src, signed char* __restrict__ q,
    float* __restrict__ scale, int ncols) {
  const int row = blockIdx.x;
  const int t = threadIdx.x;
  const float4* s4 = (const float4*)(src + (size_t)row * ncols);

  float4 v[4];
  float am = 0.f;
#pragma unroll
  for (int p = 0; p < 4; ++p) {
    v[p] = s4[p * 256 + t];
    am = fmaxf(am, fmaxf(fmaxf(fabsf(v[p].x), fabsf(v[p].y)),
                         fmaxf(fabsf(v[p].z), fabsf(v[p].w))));
  }
#pragma unroll
  for (int off = 32; off > 0; off >>= 1) am = fmaxf(am, __shfl_xor(am, off));
  __shared__ float red[4];
  if ((t & 63) == 0) red[t >> 6] = am;
  __syncthreads();
  am = fmaxf(fmaxf(red[0], red[1]), fmaxf(red[2], red[3]));

  const float s = fmaxf(am, EPSF) / QMAXF;

  uint32_t* qrow = (uint32_t*)(q + (size_t)row * ncols);
#pragma unroll
  for (int p = 0; p < 4; ++p) {
    float fx = fminf(fmaxf(rintf(v[p].x / s), -QMAXF), QMAXF);
    float fy = fminf(fmaxf(rintf(v[p].y / s), -QMAXF), QMAXF);
    float fz = fminf(fmaxf(rintf(v[p].z / s), -QMAXF), QMAXF);
    float fw = fminf(fmaxf(rintf(v[p].w / s), -QMAXF), QMAXF);
    uint32_t packed = ((uint32_t)((int)fx & 0xff)) |
                      ((uint32_t)((int)fy & 0xff) << 8) |
                      ((uint32_t)((int)fz & 0xff) << 16) |
                      ((uint32_t)((int)fw & 0xff) << 24);
    qrow[p * 256 + t] = packed;
  }
  if (t == 0) {
    float so = s;
    if (WEIGHT) so = __half2float(__float2half(s));
    scale[row] = so;
  }
}

// ---------------------------------------------------------------------------
// 256x256 8-wave int8 GEMM.
// Round-6 change vs validated round-5: merge 4 phases -> 2 WINDOWS per
// K-tile (barriers at window ends only). Race audit:
//  - w2 stages into SA0/SB0(buf d) vs w1 reads of those regions: separated
//    by the w1-end barrier (reads complete before their wave's barrier
//    arrival because every read's consumer MFMA is in w1).
//  - staged-data publication: w2-end vmcnt(4)+barrier (ledger identical to
//    validated round-3/5: invariant at each kt start, in-flight =
//    {SA0(kt+1), SB0(kt+1)}; tail drain vmcnt(0) at kt >= NKT-2).
// With 2 waves/SIMD (1 block/CU), waves de-phase within a window: one
// wave's 32-MFMA cluster overlaps the other's LDS reads.
// ---------------------------------------------------------------------------
__device__ __forceinline__ void gload16(const void* g, void* l) {
  __builtin_amdgcn_global_load_lds(
      (const __attribute__((address_space(1))) void*)g,
      (__attribute__((address_space(3))) void*)l, 16, 0, 0);
}

#define STAGE_A(dst, br0, ktoff)                                            \
  do {                                                                      \
    gload16(Ap + (size_t)((br0) + lr) * K + (ktoff) + scsw,                 \
            (dst) + ((br0) + lr) * 128 + sc);                               \
    gload16(Ap + (size_t)((br0) + 128 + lr) * K + (ktoff) + scsw,           \
            (dst) + ((br0) + 128 + lr) * 128 + sc);                         \
  } while (0)

#define STAGE_B(dst, nh, ktoff)                                             \
  do {                                                                      \
    const int r_ = (nh)*32 + lr + (lr & 32);                                \
    gload16(Bp + (size_t)(r_) * K + (ktoff) + scsw, (dst) + r_ * 128 + sc); \
    gload16(Bp + (size_t)(r_ + 128) * K + (ktoff) + scsw,                   \
            (dst) + (r_ + 128) * 128 + sc);                                 \
  } while (0)

// A-fragment set for half MH (8 x ds_read_b128 into af[4][2])
#define READ_AF(MH)                                                         \
  _Pragma("unroll") for (int mi = 0; mi < 4; ++mi)                          \
      _Pragma("unroll") for (int ks = 0; ks < 2; ++ks)                      \
          af[mi][ks] = *(const v4i*)(Ad + (arow + ((MH)*4 + mi) * 16) *     \
                                              128 +                        \
                                     ((ac0 + ks * 64) ^ axor))

// B-fragment set for half NH (4 x ds_read_b128 into dst[2][2])
#define READ_BF(dst, NH)                                                    \
  _Pragma("unroll") for (int ni = 0; ni < 2; ++ni)                          \
      _Pragma("unroll") for (int ks = 0; ks < 2; ++ks)                      \
          dst[ni][ks] = *(const v4i*)(Bd + (brow + ((NH)*2 + ni) * 16) *    \
                                               128 +                       \
                                      ((ac0 + ks * 64) ^ bxor))

// 16 MFMAs for C-quadrant (MH, NH) using af + given bf set
#define MFMA_QUAD(MH, NH, BFREG)                                            \
  _Pragma("unroll") for (int ks = 0; ks < 2; ++ks)                          \
      _Pragma("unroll") for (int mi = 0; mi < 4; ++mi)                      \
          _Pragma("unroll") for (int ni = 0; ni < 2; ++ni)                  \
              acc[(MH)*4 + mi][(NH)*2 + ni] =                               \
                  __builtin_amdgcn_mfma_i32_16x16x64_i8(                    \
                      af[mi][ks], BFREG[ni][ks],                            \
                      acc[(MH)*4 + mi][(NH)*2 + ni], 0, 0, 0)

__global__ __launch_bounds__(512, 2) void gemm_i8(
    const signed char* __restrict__ A,  // xq [M][K]
    const signed char* __restrict__ B,  // wq [N][K]
    const float* __restrict__ xsc,      // [M]
    const float* __restrict__ wsc,      // [N]
    const float* __restrict__ bias,     // [N]
    float* __restrict__ out, int M, int N, int K) {
  __shared__ __align__(16) signed char lds[131072];
  signed char* const ldsA = lds;          // [2][256][128]
  signed char* const ldsB = lds + 65536;  // [2][256][128]

  const int tid = threadIdx.x;
  const int lane = tid & 63;
  const int wid = tid >> 6;  // 0..7
  const int wm = wid >> 2;   // 0..1
  const int wn = wid & 3;    // 0..3
  const int bm0 = blockIdx.x * 256;
  const int bn0 = blockIdx.y * 256;

  const signed char* Ap = A + (size_t)bm0 * K;
  const signed char* Bp = B + (size_t)bn0 * K;

  // staging geometry (per thread): one 16B chunk of a 64-row x 128B block
  const int lr = tid >> 3;                // 0..63 row within 8KB block
  const int sc = (tid & 7) << 4;          // linear dest col byte
  const int scsw = sc ^ ((lr & 7) << 4);  // pre-swizzled SOURCE col

  // read geometry (per lane)
  const int arow = wm * 128 + (lane & 15);
  const int brow = wn * 64 + (lane & 15);
  const int ac0 = (lane >> 4) << 4;  // 16B k-chunk within 64B ksub
  const int axor = (arow & 7) << 4;
  const int bxor = (brow & 7) << 4;

  v4i acc[8][4];
#pragma unroll
  for (int i = 0; i < 8; ++i)
#pragma unroll
    for (int j = 0; j < 4; ++j) acc[i][j] = (v4i){0, 0, 0, 0};

  const int NKT = K >> 7;  // 32 K-tiles of 128 bytes

  // ---- prologue: kt0 fully + {SA0,SB0}(kt1); drain to 4 outstanding ----
  STAGE_A(ldsA, 0, 0);            // SA0(0)
  STAGE_B(ldsB, 0, 0);            // SB0(0)
  STAGE_A(ldsA, 64, 0);           // SA1(0)
  STAGE_B(ldsB, 1, 0);            // SB1(0)
  STAGE_A(ldsA + 32768, 0, 128);  // SA0(1)
  STAGE_B(ldsB + 32768, 0, 128);  // SB0(1)
  asm volatile("s_waitcnt vmcnt(4)" ::: "memory");
  __builtin_amdgcn_sched_barrier(0);
  __builtin_amdgcn_s_barrier();

  for (int kt = 0; kt < NKT; ++kt) {
    const int d = kt & 1;
    const signed char* Ad = ldsA + d * 32768;
    const signed char* Bd = ldsB + d * 32768;
    signed char* const An = ldsA + (d ^ 1) * 32768;
    signed char* const Bn = ldsB + (d ^ 1) * 32768;
    const int ko1 = (kt + 1) << 7;
    const int ko2 = (kt + 2) << 7;

    v4i af[4][2];   // A-half fragments (MH0 in w1, MH1 in w2)
    v4i bf0[2][2];  // B NH=0 fragments (read w1, used w1+w2)
    v4i bf1[2][2];  // B NH=1 fragments (read w1, used w1+w2)

    // ---- window 1: reads(16) -> stages(SA1,SB1 of kt+1) -> 32 MFMA ----
    READ_AF(0);
    READ_BF(bf0, 0);
    READ_BF(bf1, 1);
    if (kt + 1 < NKT) {
      STAGE_A(An, 64, ko1);
      STAGE_B(Bn, 1, ko1);
    }
    __builtin_amdgcn_s_setprio(1);
    MFMA_QUAD(0, 0, bf0);
    MFMA_QUAD(0, 1, bf1);
    __builtin_amdgcn_s_setprio(0);
    __builtin_amdgcn_s_barrier();

    // ---- window 2: reads(8) -> stages(SA0,SB0 of kt+2) -> 32 MFMA ----
    READ_AF(1);
    if (kt + 2 < NKT) {
      STAGE_A((signed char*)Ad, 0, ko2);
      STAGE_B((signed char*)Bd, 0, ko2);
    }
    __builtin_amdgcn_s_setprio(1);
    MFMA_QUAD(1, 0, bf0);
    MFMA_QUAD(1, 1, bf1);
    __builtin_amdgcn_s_setprio(0);
    // counted drain in steady state; full drain once staging stops
    if (kt < NKT - 2) {
      asm volatile("s_waitcnt vmcnt(4)" ::: "memory");
    } else {
      asm volatile("s_waitcnt vmcnt(0)" ::: "memory");
    }
    __builtin_amdgcn_sched_barrier(0);
    __builtin_amdgcn_s_barrier();
  }

  // ---- epilogue: dequant + fp16-roundtripped bias, fp32 store ----
#pragma unroll
  for (int mi = 0; mi < 8; ++mi) {
    const int m0 = bm0 + wm * 128 + mi * 16 + ((lane >> 4) << 2);
    const float4 xs = *(const float4*)&xsc[m0];
    const float xsv[4] = {xs.x, xs.y, xs.z, xs.w};
#pragma unroll
    for (int ni = 0; ni < 4; ++ni) {
      const int n = bn0 + wn * 64 + ni * 16 + (lane & 15);
      const float wsn = wsc[n];
      const float bn_ = __half2float(__float2half(bias[n]));
#pragma unroll
      for (int r = 0; r < 4; ++r) {
        out[(size_t)(m0 + r) * N + n] =
            (float)acc[mi][ni][r] * xsv[r] * wsn + bn_;
      }
    }
  }
}

extern "C" void kernel_launch(void* const* d_in, const int* in_sizes, int n_in,
                              void* d_out, int out_size, void* d_ws,
                              size_t ws_size, hipStream_t stream) {
  const float* x = (const float*)d_in[0];     // [M][K] fp32
  const float* w = (const float*)d_in[1];     // [N][K] fp32
  const float* bias = (const float*)d_in[2];  // [N] fp32
  float* out = (float*)d_out;

  const int K = 4096;
  const int Nw = in_sizes[1] / K;  // 4096
  const int M = in_sizes[0] / K;   // 8192

  signed char* wq = (signed char*)d_ws;
  signed char* xq = wq + (size_t)Nw * K;
  float* wsc = (float*)(xq + (size_t)M * K);
  float* xsc = wsc + Nw;

  quant_rows<true><<<Nw, 256, 0, stream>>>(w, wq, wsc, K);
  quant_rows<false><<<M, 256, 0, stream>>>(x, xq, xsc, K);

  dim3 g2(M / 256, Nw / 256, 1);
  gemm_i8<<<g2, 512, 0, stream>>>(xq, wq, xsc, wsc, bias, out, M, Nw, K);
}